// Round 1
// 333.546 us; speedup vs baseline: 1.7130x; 1.7130x over previous
//
#include <hip/hip_runtime.h>

// Pipeline: prep (f32->bf16 once) -> GEMM1+attention (bf16, M-tile 16, grid 576)
//           -> GEMM2 (bf16 m97-style, global_load_lds + XOR swizzle) -> norm.
// Workspace layout (needs ws_size >= 64,086,016 B):
//   Abf [9216][3072] bf16 = 56,623,104  (cols: 0..2047 images | 2048..2303 boxfeat | 2304..3071 tag)
//   Wf  [1024][3072] bf16 =  6,291,456  (fc_W remapped to match Abf cols; 2248..2303 zero)
//   Wa  [ 208][2816] bf16 =  1,171,456  (attn_W; rows 200..207 zero)

#define M_TOT 9216
#define K1    2816
#define K2    3072
#define ES    1024

typedef __attribute__((ext_vector_type(8))) short bf16x8;
typedef __attribute__((ext_vector_type(4))) float floatx4;

static __device__ __forceinline__ unsigned short f2bf(float f) {
    unsigned int u = __float_as_uint(f);
    u += 0x7fffu + ((u >> 16) & 1u);   // RNE
    return (unsigned short)(u >> 16);
}

// 8 consecutive f32 -> 8 bf16 (16 B store)
static __device__ __forceinline__ void cvt8(const float* __restrict__ g,
                                            unsigned short* __restrict__ d) {
    const float4 f0 = *(const float4*)g;
    const float4 f1 = *(const float4*)(g + 4);
    uint4 pk;
    pk.x = (unsigned)f2bf(f0.x) | ((unsigned)f2bf(f0.y) << 16);
    pk.y = (unsigned)f2bf(f0.z) | ((unsigned)f2bf(f0.w) << 16);
    pk.z = (unsigned)f2bf(f1.x) | ((unsigned)f2bf(f1.y) << 16);
    pk.w = (unsigned)f2bf(f1.z) | ((unsigned)f2bf(f1.w) << 16);
    *(uint4*)d = pk;
}

// async global->LDS, 16 B per lane; LDS dest = wave-uniform base + lane*16
static __device__ __forceinline__ void gl16(const void* g, const void* l) {
    __builtin_amdgcn_global_load_lds(
        (const __attribute__((address_space(1))) unsigned int*)g,
        (__attribute__((address_space(3))) unsigned int*)(unsigned int)(unsigned long long)l,
        16, 0, 0);
}

// ============ prep A: images+tag f32 -> Abf bf16 (one block per row) ============
__global__ __launch_bounds__(384) void k_prep_a(
    const float* __restrict__ images,   // [9216][2048]
    const float* __restrict__ tag,      // [9216][768]
    unsigned short* __restrict__ Abf)   // [9216][3072]
{
    const int m = blockIdx.x;
    const int t = threadIdx.x;
    unsigned short* dst = Abf + (long)m * K2;
    if (t < 256) {
        cvt8(images + (long)m * 2048 + t * 8, dst + t * 8);
    } else if (t < 352) {
        const int j = t - 256;          // 0..95
        cvt8(tag + (long)m * 768 + j * 8, dst + 2304 + j * 8);
    }
}

// ============ prep W: attn_W -> Wa, fc_W -> Wf (bf16, padded/remapped) ============
__global__ __launch_bounds__(256) void k_prep_w(
    const float* __restrict__ attn_W,   // [200][2816]
    const float* __restrict__ fc_W,     // [1024][3016]
    unsigned short* __restrict__ Wa,    // [208][2816]
    unsigned short* __restrict__ Wf)    // [1024][3072]
{
    const int u = blockIdx.x * 256 + threadIdx.x;
    uint4 z; z.x = z.y = z.z = z.w = 0u;
    if (blockIdx.y == 0) {
        if (u < 208 * 352) {
            const int r = u / 352;
            const int c = (u - r * 352) * 8;
            if (r < 200) cvt8(attn_W + (long)r * K1 + c, Wa + (long)r * K1 + c);
            else         *(uint4*)(Wa + (long)r * K1 + c) = z;
        }
    } else {
        if (u < 1024 * 384) {
            const int r = u / 384;
            const int dc = (u - r * 384) * 8;
            unsigned short* d = Wf + (long)r * K2 + dc;
            if (dc < 2248)      cvt8(fc_W + (long)r * 3016 + dc, d);        // img+box cols
            else if (dc < 2304) *(uint4*)d = z;                             // zero gap
            else                cvt8(fc_W + (long)r * 3016 + (dc - 56), d); // tag cols
        }
    }
}

// ============ GEMM1 (region = imgtag @ Wa^T) + fused attention ============
// grid 576, block 256. Block: 16 rows x 208 cols. global_load_lds staging with
// (row&7) XOR chunk swizzle -> ds_read_b128 at the bank floor.
__global__ __launch_bounds__(256, 2) void k_gemm1_attn(
    const unsigned short* __restrict__ Abf,   // [9216][3072] (reads cols !2048..2303)
    const unsigned short* __restrict__ Wa,    // [208][2816]
    const float* __restrict__ boxes,          // [9216][30]
    const float* __restrict__ pos_emb,        // [257][200]
    unsigned short* __restrict__ AbfBox)      // = Abf; writes cols 2048..2303
{
    __shared__ __align__(16) unsigned short lds[14336];   // 28,672 B
    unsigned short* ldsA = lds;          // [16][64] swizzled
    unsigned short* ldsB = lds + 1024;   // [208][64] swizzled
    float* ldsR = (float*)lds;           // [16][212] region f32 (reused after K-loop)

    const int t = threadIdx.x;
    const int lane = t & 63;
    const int w = t >> 6;
    const int quad = lane >> 4;
    const int ln15 = lane & 15;
    const int x7 = ln15 & 7;
    const int m0 = blockIdx.x * 16;
    const int lrow = lane >> 3;                 // LDS row within 8-row unit
    const int schunk = (lane & 7) ^ lrow;       // inverse-swizzled source 16B chunk
    const int nj = (w == 0) ? 4 : 3;            // wave0: j=0,4,8,12; else w,w+4,w+8

    floatx4 acc[4] = {};

    for (int kt = 0; kt < 44; ++kt) {
        const int kb = kt * 64;
        const int acol = kb + ((kb >= 2048) ? 256 : 0);   // skip boxfeat gap in Abf
#pragma unroll
        for (int i = 0; i < 7; ++i) {
            const int u = w + i * 4;            // 28 units: 0..25 = B rows, 26..27 = A
            if (u < 26) {
                const int r = u * 8 + lrow;     // 0..207
                gl16(Wa + (long)r * K1 + kb + schunk * 8, ldsB + u * 512);
            } else {
                const int r = (u - 26) * 8 + lrow;  // 0..15
                gl16(Abf + (long)(m0 + r) * K2 + acol + schunk * 8,
                     ldsA + (u - 26) * 512);
            }
        }
        __syncthreads();
#pragma unroll
        for (int s = 0; s < 2; ++s) {
            const int g = s * 4 + quad;
            const int co = (g ^ x7) << 3;       // swizzled read chunk
            const bf16x8 a = *(const bf16x8*)&ldsA[ln15 * 64 + co];
#pragma unroll
            for (int jj = 0; jj < 4; ++jj) {
                if (jj < nj) {
                    const int j = w + jj * 4;
                    const bf16x8 b = *(const bf16x8*)&ldsB[(j * 16 + ln15) * 64 + co];
                    acc[jj] = __builtin_amdgcn_mfma_f32_16x16x32_bf16(a, b, acc[jj], 0, 0, 0);
                }
            }
        }
        __syncthreads();
    }

    // region tile -> LDS f32 [16][212] (C layout: row = quad*4+reg, col = j*16+ln15)
#pragma unroll
    for (int jj = 0; jj < 4; ++jj) {
        if (jj < nj) {
            const int j = w + jj * 4;
#pragma unroll
            for (int r = 0; r < 4; ++r)
                ldsR[(quad * 4 + r) * 212 + j * 16 + ln15] = acc[jj][r];
        }
    }
    __syncthreads();

    // attention: wave w handles rows w*4 .. w*4+3
    for (int rr = 0; rr < 4; ++rr) {
        const int ml = w * 4 + rr;
        const int m = m0 + ml;
        float rv[4];
#pragma unroll
        for (int c = 0; c < 4; ++c) {
            const int e = lane + c * 64;
            rv[c] = (e < 200) ? ldsR[ml * 212 + e] : 0.0f;
        }
        const float* bx = boxes + (long)m * 30;
        int idx[15]; float bw[15], sc[15];
#pragma unroll
        for (int k = 0; k < 15; ++k) {
            int ii = (int)bx[k];
            idx[k] = (ii < 0) ? 0 : (ii > 256 ? 256 : ii);
            bw[k] = bx[15 + k];
        }
#pragma unroll
        for (int k = 0; k < 15; ++k) {
            const float* em = pos_emb + (long)idx[k] * 200;
            float p = 0.0f;
#pragma unroll
            for (int c = 0; c < 4; ++c) {
                const int e = lane + c * 64;
                if (e < 200) p += rv[c] * em[e];
            }
            for (int off = 32; off; off >>= 1) p += __shfl_xor(p, off, 64);
            sc[k] = p;
        }
        float mx = -1e30f;
#pragma unroll
        for (int k = 0; k < 15; ++k) { sc[k] = tanhf(sc[k]); mx = fmaxf(mx, sc[k]); }
        float Z = 0.0f, den = 0.0f, pk[15];
#pragma unroll
        for (int k = 0; k < 15; ++k) { pk[k] = __expf(sc[k] - mx); Z += pk[k]; }
#pragma unroll
        for (int k = 0; k < 15; ++k) { pk[k] *= bw[k]; den += pk[k]; }
        den += 1e-6f * Z;                 // softmax*w / (sum + eps) exactly
        const float inv = 1.0f / den;
        unsigned short* bo = AbfBox + (long)m * K2 + 2048;
#pragma unroll
        for (int c = 0; c < 4; ++c) {
            const int e = lane + c * 64;
            float o = 0.0f;
            if (e < 200) {
#pragma unroll
                for (int k = 0; k < 15; ++k) o += pk[k] * pos_emb[(long)idx[k] * 200 + e];
                o *= inv;
            }
            bo[e] = f2bf(o);              // cols 200..255 get exact 0
        }
    }
}

// ============ GEMM2: dout(f32) = Abf[9216][3072] @ Wf^T ============
// grid 576 (nx = bid&7 -> one fc_W N-panel per XCD L2), 128x128 tile, K=3072.
__global__ __launch_bounds__(256, 2) void k_gemm2(
    const unsigned short* __restrict__ Abf,
    const unsigned short* __restrict__ Wf,
    float* __restrict__ dout)
{
    __shared__ __align__(16) unsigned short ldsA[128 * 64];
    __shared__ __align__(16) unsigned short ldsB[128 * 64];
    const int t = threadIdx.x;
    const int lane = t & 63;
    const int w = t >> 6;
    const int quad = lane >> 4;
    const int ln15 = lane & 15;
    const int x7 = ln15 & 7;
    const int nx = blockIdx.x & 7;      // 8 XCDs round-robin consecutive bids
    const int mx = blockIdx.x >> 3;     // 0..71
    const int m0 = mx * 128;
    const int n0 = nx * 128;
    const int lrow = lane >> 3;
    const int schunk = (lane & 7) ^ lrow;
    const int wm = (w & 1) * 64;
    const int wn = (w >> 1) * 64;

    floatx4 acc[4][4] = {};

    for (int kt = 0; kt < 48; ++kt) {
        const int kb = kt * 64;
#pragma unroll
        for (int i = 0; i < 4; ++i) {
            const int u = w * 4 + i;            // 0..15: 8-row groups
            const int r = u * 8 + lrow;         // 0..127
            gl16(Abf + (long)(m0 + r) * K2 + kb + schunk * 8, ldsA + u * 512);
            gl16(Wf  + (long)(n0 + r) * K2 + kb + schunk * 8, ldsB + u * 512);
        }
        __syncthreads();
#pragma unroll
        for (int s = 0; s < 2; ++s) {
            const int g = s * 4 + quad;
            const int co = (g ^ x7) << 3;
            bf16x8 a[4], b[4];
#pragma unroll
            for (int i = 0; i < 4; ++i)
                a[i] = *(const bf16x8*)&ldsA[(wm + i * 16 + ln15) * 64 + co];
#pragma unroll
            for (int j = 0; j < 4; ++j)
                b[j] = *(const bf16x8*)&ldsB[(wn + j * 16 + ln15) * 64 + co];
#pragma unroll
            for (int i = 0; i < 4; ++i)
#pragma unroll
                for (int j = 0; j < 4; ++j)
                    acc[i][j] = __builtin_amdgcn_mfma_f32_16x16x32_bf16(a[i], b[j], acc[i][j], 0, 0, 0);
        }
        __syncthreads();
    }
#pragma unroll
    for (int i = 0; i < 4; ++i)
#pragma unroll
        for (int j = 0; j < 4; ++j) {
            const int row = m0 + wm + i * 16 + quad * 4;
            const int col = n0 + wn + j * 16 + ln15;
#pragma unroll
            for (int r = 0; r < 4; ++r)
                dout[(long)(row + r) * ES + col] = acc[i][j][r];
        }
}

// ============ bias + L2 normalize, IN-PLACE in d_out (f32) ============
__global__ __launch_bounds__(256) void k_norm(
    float* __restrict__ dout,
    const float* __restrict__ bias)
{
    __shared__ float red[4];
    const int m = blockIdx.x;
    const int t = threadIdx.x;
    float* f = dout + (long)m * ES + t * 4;
    float4 v = *(const float4*)f;
    const float4 bs = *(const float4*)(bias + t * 4);
    v.x += bs.x; v.y += bs.y; v.z += bs.z; v.w += bs.w;
    float ss = v.x * v.x + v.y * v.y + v.z * v.z + v.w * v.w;
    for (int off = 32; off; off >>= 1) ss += __shfl_xor(ss, off, 64);
    if ((t & 63) == 0) red[t >> 6] = ss;
    __syncthreads();
    const float total = red[0] + red[1] + red[2] + red[3];
    const float inv = 1.0f / (sqrtf(total) + 1e-8f);
    float4 o;
    o.x = v.x * inv; o.y = v.y * inv; o.z = v.z * inv; o.w = v.w * inv;
    *(float4*)f = o;
}

// ============ launch ============
extern "C" void kernel_launch(void* const* d_in, const int* in_sizes, int n_in,
                              void* d_out, int out_size, void* d_ws, size_t ws_size,
                              hipStream_t stream) {
    const float* images  = (const float*)d_in[0];
    const float* tag     = (const float*)d_in[1];
    const float* boxes   = (const float*)d_in[2];
    const float* pos_emb = (const float*)d_in[3];
    const float* attn_W  = (const float*)d_in[4];
    const float* fc_W    = (const float*)d_in[5];
    const float* fc_b    = (const float*)d_in[6];
    float* out = (float*)d_out;

    unsigned short* Abf = (unsigned short*)d_ws;            // 56,623,104 B
    unsigned short* Wf  = Abf + (size_t)M_TOT * K2;         //  6,291,456 B
    unsigned short* Wa  = Wf  + (size_t)ES * K2;            //  1,171,456 B
    // total workspace: 64,086,016 B

    k_prep_a    <<<M_TOT, 384, 0, stream>>>(images, tag, Abf);
    k_prep_w    <<<dim3(1536, 2), 256, 0, stream>>>(attn_W, fc_W, Wa, Wf);
    k_gemm1_attn<<<576, 256, 0, stream>>>(Abf, Wa, boxes, pos_emb, Abf);
    k_gemm2     <<<576, 256, 0, stream>>>(Abf, Wf, out);
    k_norm      <<<M_TOT, 256, 0, stream>>>(out, fc_b);
}